// Round 3
// baseline (5751.246 us; speedup 1.0000x reference)
//
#include <hip/hip_runtime.h>

typedef __attribute__((ext_vector_type(8))) short bf16x8_t;
typedef __attribute__((ext_vector_type(4))) float f32x4_t;

__device__ __forceinline__ ushort f2bf(float x) {
  union { float f; unsigned u; } a; a.f = x;
  unsigned r = a.u + 0x7fffu + ((a.u >> 16) & 1u);
  return (ushort)(r >> 16);
}
__device__ __forceinline__ float bf2f(ushort s) {
  union { unsigned u; float f; } a; a.u = ((unsigned)s) << 16;
  return a.f;
}
__device__ __forceinline__ void gload_lds16(const void* g, void* l) {
  __builtin_amdgcn_global_load_lds(
      (const __attribute__((address_space(1))) unsigned int*)g,
      (__attribute__((address_space(3))) unsigned int*)l, 16, 0, 0);
}
__device__ __forceinline__ int swzkey(int r) { return ((r >> 2) ^ r) & 3; }

// ---------------- weight conversion ----------------
__global__ void cvt_kernel(const float* __restrict__ s, ushort* __restrict__ d, int n) {
  int i = blockIdx.x * 256 + threadIdx.x;
  if (i < n) d[i] = f2bf(s[i]);
}

__global__ void cvt4_kernel(const float* __restrict__ s, ushort* __restrict__ d, long n4) {
  long i = (long)blockIdx.x * 256 + threadIdx.x;
  if (i < n4) {
    float4 v = ((const float4*)s)[i];
    ushort4 o;
    o.x = f2bf(v.x); o.y = f2bf(v.y); o.z = f2bf(v.z); o.w = f2bf(v.w);
    ((ushort4*)d)[i] = o;
  }
}

// Wcat[l][r][c], r: 0-63 A_w, 64-127 B_w, 128-383 gate_w, 384-639 D_w
__global__ void build_wcat(const float* __restrict__ Aw, const float* __restrict__ Bw,
                           const float* __restrict__ gw, const float* __restrict__ Dw,
                           ushort* __restrict__ out) {
  int i = blockIdx.x * 256 + threadIdx.x;
  if (i >= 6 * 640 * 256) return;
  int l = i / (640 * 256), r = (i / 256) % 640, c = i % 256;
  float v;
  if (r < 64)        v = Aw[((l * 64 + r) * 256) + c];
  else if (r < 128)  v = Bw[((l * 64 + (r - 64)) * 256) + c];
  else if (r < 384)  v = gw[((l * 256 + (r - 128)) * 256) + c];
  else               v = Dw[((l * 256 + (r - 384)) * 256) + c];
  out[i] = f2bf(v);
}

// ========== G1: W-resident GEMM, 128-wide N panel, persistent over M-tiles ==========
// out = epi(A[M,K]bf16 @ W[N,K]bf16^T), panel n0 = blockIdx.y*128.
// MODE 1: bf16 out, col<64 tanh | <128 id | <384 sigmoid(v+b1[col-128]) | else v+b2[col-384]
// MODE 2: bf16 out = gelu_exact(v + b1[col])
template <int K, int MODE>
__global__ __launch_bounds__(256, 2)
void gemm_wres(const ushort* __restrict__ A, const ushort* __restrict__ W,
               const float* __restrict__ b1, const float* __restrict__ b2,
               ushort* __restrict__ outp, int N, int mtiles) {
  constexpr int KS = K / 32;
  __shared__ __align__(16) char WsB[KS * 8192];   // resident W panel [ks][128 rows][64B]
  __shared__ __align__(16) char AsB[2 * 8192];    // double-buffered A tile

  const int t = threadIdx.x, lane = t & 63, wid = t >> 6;
  const int n0 = blockIdx.y * 128;
  const int wr = (wid >> 1) * 64, wc = (wid & 1) * 64;
  const int lr = lane >> 2, lc = lane & 3;
  const int ca = wid * 2;                 // chunk ids ca, ca+1 (8 x 1KB chunks)
  const int ra0 = ca * 16 + lr, ra1 = ra0 + 16;
  const int sa0 = (lc ^ swzkey(ra0)) << 4;
  const int sa1 = (lc ^ swzkey(ra1)) << 4;
  const char* Ab = (const char*)A;
  const char* Wb = (const char*)W;
  constexpr long K2 = (long)K * 2;

  // preload resident W panel
#pragma unroll
  for (int ks = 0; ks < KS; ++ks) {
    gload_lds16(Wb + (long)(n0 + ra0) * K2 + ks * 64 + sa0, WsB + ks * 8192 + ca * 1024);
    gload_lds16(Wb + (long)(n0 + ra1) * K2 + ks * 64 + sa1, WsB + ks * 8192 + ca * 1024 + 1024);
  }

  const int krow = lane & 15, kslot = lane >> 4;
  int aoff[4], boff[4];
#pragma unroll
  for (int i = 0; i < 4; ++i) {
    int ar = wr + i * 16 + krow;
    aoff[i] = ar * 64 + ((kslot ^ swzkey(ar)) << 4);
    int br = wc + i * 16 + krow;
    boff[i] = br * 64 + ((kslot ^ swzkey(br)) << 4);
  }

  const f32x4_t zero = {0.f, 0.f, 0.f, 0.f};
  f32x4_t acc[4][4];
#pragma unroll
  for (int i = 0; i < 4; ++i)
#pragma unroll
    for (int j = 0; j < 4; ++j) acc[i][j] = zero;

  const int T = mtiles * KS;
  // stage A for tau=0
  {
    const long m0 = (long)blockIdx.x * 128;
    gload_lds16(Ab + (m0 + ra0) * K2 + sa0, AsB + ca * 1024);
    gload_lds16(Ab + (m0 + ra1) * K2 + sa1, AsB + ca * 1024 + 1024);
  }

  const int rbase = (lane >> 4) * 4;
  const int cbase = lane & 15;

  for (int tau = 0; tau < T; ++tau) {
    __syncthreads();  // buf[tau&1] staged; prior reads of buf[(tau+1)&1] done
    if (tau + 1 < T) {
      const int tn = tau + 1;
      const long m0n = ((long)blockIdx.x + (long)(tn / KS) * gridDim.x) * 128;
      const long kb = (long)(tn % KS) * 64;
      char* dst = AsB + (tn & 1) * 8192 + ca * 1024;
      gload_lds16(Ab + (m0n + ra0) * K2 + kb + sa0, dst);
      gload_lds16(Ab + (m0n + ra1) * K2 + kb + sa1, dst + 1024);
    }
    const char* Ac = AsB + (tau & 1) * 8192;
    const char* Wc = WsB + (tau % KS) * 8192;
    bf16x8_t af[4], bv[4];
#pragma unroll
    for (int i = 0; i < 4; ++i) af[i] = *(const bf16x8_t*)(Ac + aoff[i]);
#pragma unroll
    for (int i = 0; i < 4; ++i) bv[i] = *(const bf16x8_t*)(Wc + boff[i]);
#pragma unroll
    for (int mi = 0; mi < 4; ++mi)
#pragma unroll
      for (int ni = 0; ni < 4; ++ni)
        acc[mi][ni] = __builtin_amdgcn_mfma_f32_16x16x32_bf16(af[mi], bv[ni], acc[mi][ni], 0, 0, 0);

    if ((tau % KS) == KS - 1) {
      const long m0 = ((long)blockIdx.x + (long)(tau / KS) * gridDim.x) * 128;
#pragma unroll
      for (int mi = 0; mi < 4; ++mi) {
#pragma unroll
        for (int ni = 0; ni < 4; ++ni) {
          const int col = n0 + wc + ni * 16 + cbase;
#pragma unroll
          for (int j = 0; j < 4; ++j) {
            const long row = m0 + wr + mi * 16 + rbase + j;
            float v = acc[mi][ni][j];
            float o;
            if constexpr (MODE == 1) {
              if (col < 64)       o = tanhf(v);
              else if (col < 128) o = v;
              else if (col < 384) { float s = v + b1[col - 128]; o = 1.f / (1.f + expf(-s)); }
              else                o = v + b2[col - 384];
            } else {
              float s = v + b1[col];
              o = 0.5f * s * (1.f + erff(s * 0.70710678118654752f));
            }
            outp[row * N + col] = f2bf(o);
          }
          acc[mi][ni] = zero;
        }
      }
    }
  }
}

// ========== G2: N=256 full-row GEMM with fused residual + LayerNorm ==========
// MODE 0: xnew = v + b1[col]                       (input projection)
// MODE 3: xnew = x[row,col] + v + b1[col]          (ffn2 residual)
// MODE 4: xnew = x[row,col] + v*g + dt*(1-g)       (C-mix combine; g,dt from zgd)
// Then per row: y = (xnew-mean)*rstd*lng + lnb (bf16); x written iff writex.
template <int K, int MODE, bool WRES>
__global__ __launch_bounds__(512, 4)
void gemm_ln(const ushort* __restrict__ A, const ushort* __restrict__ W,
             const float* __restrict__ b1, const ushort* __restrict__ zgd,
             float* __restrict__ x, const float* __restrict__ lng,
             const float* __restrict__ lnb, ushort* __restrict__ y,
             int writex, int mtiles) {
  constexpr int KS = K / 32;
  __shared__ __align__(16) char WsB[2 * 16384];   // W slice(s): [buf|ks][256 rows][64B]
  __shared__ __align__(16) char AsB[2 * 8192];    // A tile double-buffered
  __shared__ float lsum4[128][4], lsq4[128][4];

  const int t = threadIdx.x, lane = t & 63, wid = t >> 6;
  const int wr = (wid >> 2) * 64, wc = (wid & 3) * 64;
  const int lr = lane >> 2, lc = lane & 3;
  const int ra = wid * 16 + lr;                   // A rows (8 chunks, 1/wave)
  const int saA = (lc ^ swzkey(ra)) << 4;
  const int rw0 = wid * 32 + lr, rw1 = rw0 + 16;  // W rows (16 chunks, 2/wave)
  const int sw0 = (lc ^ swzkey(rw0)) << 4;
  const int sw1 = (lc ^ swzkey(rw1)) << 4;
  const char* Ab = (const char*)A;
  const char* Wb = (const char*)W;
  constexpr long K2 = (long)K * 2;

  if constexpr (WRES) {
#pragma unroll
    for (int ks = 0; ks < KS; ++ks) {
      gload_lds16(Wb + (long)rw0 * K2 + ks * 64 + sw0, WsB + ks * 16384 + wid * 2048);
      gload_lds16(Wb + (long)rw1 * K2 + ks * 64 + sw1, WsB + ks * 16384 + wid * 2048 + 1024);
    }
  } else {
    gload_lds16(Wb + (long)rw0 * K2 + sw0, WsB + wid * 2048);
    gload_lds16(Wb + (long)rw1 * K2 + sw1, WsB + wid * 2048 + 1024);
  }
  {
    const long m0 = (long)blockIdx.x * 128;
    gload_lds16(Ab + (m0 + ra) * K2 + saA, AsB + wid * 1024);
  }

  const int krow = lane & 15, kslot = lane >> 4;
  int aoff[4], boff[4];
#pragma unroll
  for (int i = 0; i < 4; ++i) {
    int ar = wr + i * 16 + krow;
    aoff[i] = ar * 64 + ((kslot ^ swzkey(ar)) << 4);
    int br = wc + i * 16 + krow;
    boff[i] = br * 64 + ((kslot ^ swzkey(br)) << 4);
  }

  const f32x4_t zero = {0.f, 0.f, 0.f, 0.f};
  f32x4_t acc[4][4];
#pragma unroll
  for (int i = 0; i < 4; ++i)
#pragma unroll
    for (int j = 0; j < 4; ++j) acc[i][j] = zero;

  const int T = mtiles * KS;
  const int rbase = (lane >> 4) * 4;
  const int cbase = lane & 15;

  for (int tau = 0; tau < T; ++tau) {
    __syncthreads();
    if (tau + 1 < T) {
      const int tn = tau + 1;
      const long m0n = ((long)blockIdx.x + (long)(tn / KS) * gridDim.x) * 128;
      const long kb = (long)(tn % KS) * 64;
      gload_lds16(Ab + (m0n + ra) * K2 + kb + saA, AsB + (tn & 1) * 8192 + wid * 1024);
      if constexpr (!WRES) {
        char* wd = WsB + (tn & 1) * 16384 + wid * 2048;
        gload_lds16(Wb + (long)rw0 * K2 + kb + sw0, wd);
        gload_lds16(Wb + (long)rw1 * K2 + kb + sw1, wd + 1024);
      }
    }
    const char* Ac = AsB + (tau & 1) * 8192;
    const char* Wc = WsB + (WRES ? (tau % KS) : (tau & 1)) * 16384;
    bf16x8_t af[4], bv[4];
#pragma unroll
    for (int i = 0; i < 4; ++i) af[i] = *(const bf16x8_t*)(Ac + aoff[i]);
#pragma unroll
    for (int i = 0; i < 4; ++i) bv[i] = *(const bf16x8_t*)(Wc + boff[i]);
#pragma unroll
    for (int mi = 0; mi < 4; ++mi)
#pragma unroll
      for (int ni = 0; ni < 4; ++ni)
        acc[mi][ni] = __builtin_amdgcn_mfma_f32_16x16x32_bf16(af[mi], bv[ni], acc[mi][ni], 0, 0, 0);

    if ((tau % KS) == KS - 1) {
      const long m0 = ((long)blockIdx.x + (long)(tau / KS) * gridDim.x) * 128;
      // 1) residual -> acc holds xnew
#pragma unroll
      for (int mi = 0; mi < 4; ++mi) {
#pragma unroll
        for (int ni = 0; ni < 4; ++ni) {
          const int col = wc + ni * 16 + cbase;
#pragma unroll
          for (int j = 0; j < 4; ++j) {
            const long row = m0 + wr + mi * 16 + rbase + j;
            float v = acc[mi][ni][j];
            if constexpr (MODE == 0) {
              v += b1[col];
            } else if constexpr (MODE == 3) {
              v += b1[col] + x[row * 256 + col];
            } else {
              float gv = bf2f(zgd[row * 640 + 128 + col]);
              float dv = bf2f(zgd[row * 640 + 384 + col]);
              v = x[row * 256 + col] + v * gv + dv * (1.f - gv);
            }
            acc[mi][ni][j] = v;
          }
        }
      }
      // 2) per-row partial stats (16 lanes share rows within a quarter)
#pragma unroll
      for (int mi = 0; mi < 4; ++mi) {
#pragma unroll
        for (int j = 0; j < 4; ++j) {
          float ps = 0.f, pq = 0.f;
#pragma unroll
          for (int ni = 0; ni < 4; ++ni) { float v = acc[mi][ni][j]; ps += v; pq += v * v; }
#pragma unroll
          for (int off = 1; off < 16; off <<= 1) {
            ps += __shfl_xor(ps, off, 64);
            pq += __shfl_xor(pq, off, 64);
          }
          if ((lane & 15) == 0) {
            int r = wr + mi * 16 + (lane >> 4) * 4 + j;
            lsum4[r][wid & 3] = ps;
            lsq4[r][wid & 3] = pq;
          }
        }
      }
      __syncthreads();
      // 3) normalize + store x (fp32) and y (bf16)
#pragma unroll
      for (int mi = 0; mi < 4; ++mi) {
#pragma unroll
        for (int j = 0; j < 4; ++j) {
          const int r = wr + mi * 16 + rbase + j;
          const float s = lsum4[r][0] + lsum4[r][1] + lsum4[r][2] + lsum4[r][3];
          const float q = lsq4[r][0] + lsq4[r][1] + lsq4[r][2] + lsq4[r][3];
          const float mean = s * (1.f / 256.f);
          const float rstd = rsqrtf(q * (1.f / 256.f) - mean * mean + 1e-5f);
          const long row = m0 + r;
#pragma unroll
          for (int ni = 0; ni < 4; ++ni) {
            const int col = wc + ni * 16 + cbase;
            const float v = acc[mi][ni][j];
            if (writex) x[row * 256 + col] = v;
            y[row * 256 + col] = f2bf((v - mean) * rstd * lng[col] + lnb[col]);
          }
        }
      }
#pragma unroll
      for (int mi = 0; mi < 4; ++mi)
#pragma unroll
        for (int ni = 0; ni < 4; ++ni) acc[mi][ni] = zero;
    }
  }
}

// ---------------- scan: h[s] = a[s]*h[s-1] + bt[s], one lane per (batch, dim) -------------
__global__ __launch_bounds__(256)
void scan_kernel(const ushort* __restrict__ z, ushort* __restrict__ hs) {
  const long tid = (long)blockIdx.x * 256 + threadIdx.x;
  const long b = tid >> 6;
  const int d = tid & 63;
  const ushort* zb = z + b * (16 * 640);
  ushort* hb = hs + b * (16 * 64);
  float h = 0.f;
#pragma unroll
  for (int s = 0; s < 16; ++s) {
    float a  = bf2f(zb[s * 640 + d]);
    float bt = bf2f(zb[s * 640 + 64 + d]);
    h = fmaf(a, h, bt);
    hb[s * 64 + d] = f2bf(h);
  }
}

// ---------------- head: neighbor attention + MLP + log_softmax (input pre-LN'd, bf16) -----
__global__ __launch_bounds__(256)
void head_kernel(const ushort* __restrict__ yin, const float* __restrict__ attw,
                 const float* __restrict__ ow, const float* __restrict__ ob,
                 const float* __restrict__ cw, const float* __restrict__ cb,
                 float* __restrict__ out) {
  __shared__ float xf[16][256];
  __shared__ float lg[16], aw[16];
  __shared__ float vs[256], o1[128], lgc[40], lse[1];
  const int t = threadIdx.x, lane = t & 63, wid = t >> 6;
  const ushort* yb = yin + (long)blockIdx.x * 16 * 256;

  for (int r = wid; r < 16; r += 4) {
    ushort4 u = *(const ushort4*)(yb + r * 256 + lane * 4);
    int c = lane * 4;
    xf[r][c + 0] = bf2f(u.x);
    xf[r][c + 1] = bf2f(u.y);
    xf[r][c + 2] = bf2f(u.z);
    xf[r][c + 3] = bf2f(u.w);
  }
  __syncthreads();

  for (int r = wid; r < 16; r += 4) {
    const float* wv = attw + (r == 0 ? 0 : 256);
    int c = lane * 4;
    float s = xf[r][c] * wv[c] + xf[r][c + 1] * wv[c + 1] +
              xf[r][c + 2] * wv[c + 2] + xf[r][c + 3] * wv[c + 3];
#pragma unroll
    for (int off = 32; off > 0; off >>= 1) s += __shfl_xor(s, off, 64);
    if (lane == 0) lg[r] = s;
  }
  __syncthreads();

  if (t == 0) {
    float mx = -1e30f;
    for (int s2 = 1; s2 < 16; ++s2) mx = fmaxf(mx, lg[s2]);
    float den = 0.f;
    for (int s2 = 1; s2 < 16; ++s2) { float e = expf(lg[s2] - mx); aw[s2] = e; den += e; }
    float inv = 1.f / den;
    for (int s2 = 1; s2 < 16; ++s2) aw[s2] *= inv;
  }
  __syncthreads();

  float vh = xf[0][t];
  for (int s2 = 1; s2 < 16; ++s2) vh += aw[s2] * xf[s2][t];
  vs[t] = vh;
  __syncthreads();

  if (t < 128) {
    float s = ob[t];
    const float* w = ow + t * 256;
    for (int h2 = 0; h2 < 256; ++h2) s += w[h2] * vs[h2];
    o1[t] = fmaxf(s, 0.f);
  }
  __syncthreads();

  if (t < 40) {
    float s = cb[t];
    const float* w = cw + t * 128;
    for (int j = 0; j < 128; ++j) s += w[j] * o1[j];
    lgc[t] = s;
  }
  __syncthreads();

  if (t == 0) {
    float mx = -1e30f;
    for (int c2 = 0; c2 < 40; ++c2) mx = fmaxf(mx, lgc[c2]);
    float den = 0.f;
    for (int c2 = 0; c2 < 40; ++c2) den += expf(lgc[c2] - mx);
    lse[0] = mx + logf(den);
  }
  __syncthreads();
  if (t < 40) out[(long)blockIdx.x * 40 + t] = lgc[t] - lse[0];
}

// ---------------- host ----------------
extern "C" void kernel_launch(void* const* d_in, const int* in_sizes, int n_in,
                              void* d_out, int out_size, void* d_ws, size_t ws_size,
                              hipStream_t stream) {
  const float* data   = (const float*)d_in[0];
  const float* in_w   = (const float*)d_in[1];
  const float* in_b   = (const float*)d_in[2];
  const float* norm_g = (const float*)d_in[3];
  const float* norm_b = (const float*)d_in[4];
  const float* A_w    = (const float*)d_in[5];
  const float* B_w    = (const float*)d_in[6];
  const float* C_w    = (const float*)d_in[7];
  const float* D_w    = (const float*)d_in[8];
  const float* D_b    = (const float*)d_in[9];
  const float* gate_w = (const float*)d_in[10];
  const float* gate_b = (const float*)d_in[11];
  const float* ffn_w1 = (const float*)d_in[12];
  const float* ffn_b1 = (const float*)d_in[13];
  const float* ffn_w2 = (const float*)d_in[14];
  const float* ffn_b2 = (const float*)d_in[15];
  const float* fln_g  = (const float*)d_in[16];
  const float* fln_b  = (const float*)d_in[17];
  const float* out_w  = (const float*)d_in[18];
  const float* out_b  = (const float*)d_in[19];
  const float* cls_w  = (const float*)d_in[20];
  const float* cls_b  = (const float*)d_in[21];
  const float* attn_w = (const float*)d_in[22];
  const float* attn_b = (const float*)d_in[23];
  (void)in_sizes; (void)n_in; (void)out_size; (void)ws_size; (void)attn_b; (void)fln_b;

  char* ws = (char*)d_ws;
  float*  x    = (float*)(ws + 0);            // 131072*256*4  = 134217728
  ushort* y    = (ushort*)(ws + 134217728);   // 131072*256*2  =  67108864
  ushort* z    = (ushort*)(ws + 201326592);   // 131072*640*2  = 167772160 (reused: datab, ffn1 t)
  ushort* hs   = (ushort*)(ws + 369098752);   // 131072*64*2   =  16777216
  ushort* wcat = (ushort*)(ws + 385875968);   // 6*640*256*2   =   1966080
  ushort* inwb = (ushort*)(ws + 387842048);   // 256*512*2     =    262144
  ushort* w1b  = (ushort*)(ws + 388104192);   // 6*512*256*2   =   1572864
  ushort* w2b  = (ushort*)(ws + 389677056);   // 6*256*512*2   =   1572864
  ushort* cwb  = (ushort*)(ws + 391249920);   // 6*256*64*2    =    196608
  ushort* datab = z;                          // consumed by input proj before z written

  cvt_kernel<<<512, 256, 0, stream>>>(in_w, inwb, 131072);
  cvt_kernel<<<3072, 256, 0, stream>>>(ffn_w1, w1b, 786432);
  cvt_kernel<<<3072, 256, 0, stream>>>(ffn_w2, w2b, 786432);
  cvt_kernel<<<384, 256, 0, stream>>>(C_w, cwb, 98304);
  build_wcat<<<3840, 256, 0, stream>>>(A_w, B_w, gate_w, D_w, wcat);
  cvt4_kernel<<<65536, 256, 0, stream>>>(data, datab, 16777216);

  // input proj + fused LN(layer0): x, y
  gemm_ln<512, 0, false><<<dim3(1024), 512, 0, stream>>>(
      datab, inwb, in_b, nullptr, x, norm_g, norm_b, y, 1, 1);

  for (int l = 0; l < 6; ++l) {
    gemm_wres<256, 1><<<dim3(256, 5), 256, 0, stream>>>(
        y, wcat + (size_t)l * 640 * 256, gate_b + l * 256, D_b + l * 256, z, 640, 4);
    scan_kernel<<<2048, 256, 0, stream>>>(z, hs);
    // C-mix + combine + fused LN(layer l): x, y
    gemm_ln<64, 4, true><<<dim3(512), 512, 0, stream>>>(
        hs, cwb + (size_t)l * 256 * 64, nullptr, z, x, norm_g + l * 256, norm_b + l * 256,
        y, 1, 2);
    gemm_wres<256, 2><<<dim3(256, 4), 256, 0, stream>>>(
        y, w1b + (size_t)l * 512 * 256, ffn_b1 + l * 512, nullptr, z, 512, 4);
    // ffn2 + residual + fused LN(layer l+1 or final): x (skipped on last), y
    const float* lg2 = (l < 5) ? (norm_g + (l + 1) * 256) : fln_g;
    const float* lb2 = (l < 5) ? (norm_b + (l + 1) * 256) : fln_b;
    gemm_ln<512, 3, false><<<dim3(1024), 512, 0, stream>>>(
        z, w2b + (size_t)l * 256 * 512, ffn_b2 + l * 256, nullptr, x, lg2, lb2,
        y, (l < 5) ? 1 : 0, 1);
  }

  head_kernel<<<8192, 256, 0, stream>>>(y, attn_w, out_w, out_b, cls_w, cls_b, (float*)d_out);
}

// Round 4
// 3376.383 us; speedup vs baseline: 1.7034x; 1.7034x over previous
//
#include <hip/hip_runtime.h>

typedef __attribute__((ext_vector_type(8))) short bf16x8_t;
typedef __attribute__((ext_vector_type(4))) float f32x4_t;

__device__ __forceinline__ ushort f2bf(float x) {
  union { float f; unsigned u; } a; a.f = x;
  unsigned r = a.u + 0x7fffu + ((a.u >> 16) & 1u);
  return (ushort)(r >> 16);
}
__device__ __forceinline__ float bf2f(ushort s) {
  union { unsigned u; float f; } a; a.u = ((unsigned)s) << 16;
  return a.f;
}
__device__ __forceinline__ void gload_lds16(const void* g, void* l) {
  __builtin_amdgcn_global_load_lds(
      (const __attribute__((address_space(1))) unsigned int*)g,
      (__attribute__((address_space(3))) unsigned int*)l, 16, 0, 0);
}
__device__ __forceinline__ int swzkey(int r) { return ((r >> 2) ^ r) & 3; }

// ---------------- weight conversion ----------------
__global__ void cvt_kernel(const float* __restrict__ s, ushort* __restrict__ d, int n) {
  int i = blockIdx.x * 256 + threadIdx.x;
  if (i < n) d[i] = f2bf(s[i]);
}

__global__ void cvt4_kernel(const float* __restrict__ s, ushort* __restrict__ d, long n4) {
  long i = (long)blockIdx.x * 256 + threadIdx.x;
  if (i < n4) {
    float4 v = ((const float4*)s)[i];
    ushort4 o;
    o.x = f2bf(v.x); o.y = f2bf(v.y); o.z = f2bf(v.z); o.w = f2bf(v.w);
    ((ushort4*)d)[i] = o;
  }
}

// Wcat[l][r][c], r: 0-63 A_w, 64-127 B_w, 128-383 gate_w, 384-639 D_w
__global__ void build_wcat(const float* __restrict__ Aw, const float* __restrict__ Bw,
                           const float* __restrict__ gw, const float* __restrict__ Dw,
                           ushort* __restrict__ out) {
  int i = blockIdx.x * 256 + threadIdx.x;
  if (i >= 6 * 640 * 256) return;
  int l = i / (640 * 256), r = (i / 256) % 640, c = i % 256;
  float v;
  if (r < 64)        v = Aw[((l * 64 + r) * 256) + c];
  else if (r < 128)  v = Bw[((l * 64 + (r - 64)) * 256) + c];
  else if (r < 384)  v = gw[((l * 256 + (r - 128)) * 256) + c];
  else               v = Dw[((l * 256 + (r - 384)) * 256) + c];
  out[i] = f2bf(v);
}

// ========== G1: W-resident GEMM, 128-wide N panel, persistent over M-tiles ==========
// MODE 1: bf16 out, col<64 tanh | <128 id | <384 sigmoid(v+b1[col-128]) | else v+b2[col-384]
// MODE 2: bf16 out = gelu_exact(v + b1[col])
template <int K, int MODE>
__global__ __launch_bounds__(256, 2)
void gemm_wres(const ushort* __restrict__ A, const ushort* __restrict__ W,
               const float* __restrict__ b1, const float* __restrict__ b2,
               ushort* __restrict__ outp, int N, int mtiles) {
  constexpr int KS = K / 32;
  __shared__ __align__(16) char WsB[KS * 8192];   // resident W panel [ks][128 rows][64B]
  __shared__ __align__(16) char AsB[2 * 8192];    // double-buffered A tile

  const int t = threadIdx.x, lane = t & 63, wid = t >> 6;
  const int n0 = blockIdx.y * 128;
  const int wr = (wid >> 1) * 64, wc = (wid & 1) * 64;
  const int lr = lane >> 2, lc = lane & 3;
  const int ca = wid * 2;
  const int ra0 = ca * 16 + lr, ra1 = ra0 + 16;
  const int sa0 = (lc ^ swzkey(ra0)) << 4;
  const int sa1 = (lc ^ swzkey(ra1)) << 4;
  const char* Ab = (const char*)A;
  const char* Wb = (const char*)W;
  constexpr long K2 = (long)K * 2;

#pragma unroll
  for (int ks = 0; ks < KS; ++ks) {
    gload_lds16(Wb + (long)(n0 + ra0) * K2 + ks * 64 + sa0, WsB + ks * 8192 + ca * 1024);
    gload_lds16(Wb + (long)(n0 + ra1) * K2 + ks * 64 + sa1, WsB + ks * 8192 + ca * 1024 + 1024);
  }

  const int krow = lane & 15, kslot = lane >> 4;
  int aoff[4], boff[4];
#pragma unroll
  for (int i = 0; i < 4; ++i) {
    int ar = wr + i * 16 + krow;
    aoff[i] = ar * 64 + ((kslot ^ swzkey(ar)) << 4);
    int br = wc + i * 16 + krow;
    boff[i] = br * 64 + ((kslot ^ swzkey(br)) << 4);
  }

  const f32x4_t zero = {0.f, 0.f, 0.f, 0.f};
  f32x4_t acc[4][4];
#pragma unroll
  for (int i = 0; i < 4; ++i)
#pragma unroll
    for (int j = 0; j < 4; ++j) acc[i][j] = zero;

  const int T = mtiles * KS;
  {
    const long m0 = (long)blockIdx.x * 128;
    gload_lds16(Ab + (m0 + ra0) * K2 + sa0, AsB + ca * 1024);
    gload_lds16(Ab + (m0 + ra1) * K2 + sa1, AsB + ca * 1024 + 1024);
  }

  const int rbase = (lane >> 4) * 4;
  const int cbase = lane & 15;

  for (int tau = 0; tau < T; ++tau) {
    __syncthreads();
    if (tau + 1 < T) {
      const int tn = tau + 1;
      const long m0n = ((long)blockIdx.x + (long)(tn / KS) * gridDim.x) * 128;
      const long kb = (long)(tn % KS) * 64;
      char* dst = AsB + (tn & 1) * 8192 + ca * 1024;
      gload_lds16(Ab + (m0n + ra0) * K2 + kb + sa0, dst);
      gload_lds16(Ab + (m0n + ra1) * K2 + kb + sa1, dst + 1024);
    }
    const char* Ac = AsB + (tau & 1) * 8192;
    const char* Wc = WsB + (tau % KS) * 8192;
    bf16x8_t af[4], bv[4];
#pragma unroll
    for (int i = 0; i < 4; ++i) af[i] = *(const bf16x8_t*)(Ac + aoff[i]);
#pragma unroll
    for (int i = 0; i < 4; ++i) bv[i] = *(const bf16x8_t*)(Wc + boff[i]);
#pragma unroll
    for (int mi = 0; mi < 4; ++mi)
#pragma unroll
      for (int ni = 0; ni < 4; ++ni)
        acc[mi][ni] = __builtin_amdgcn_mfma_f32_16x16x32_bf16(af[mi], bv[ni], acc[mi][ni], 0, 0, 0);

    if ((tau % KS) == KS - 1) {
      const long m0 = ((long)blockIdx.x + (long)(tau / KS) * gridDim.x) * 128;
#pragma unroll
      for (int mi = 0; mi < 4; ++mi) {
#pragma unroll
        for (int ni = 0; ni < 4; ++ni) {
          const int col = n0 + wc + ni * 16 + cbase;
#pragma unroll
          for (int j = 0; j < 4; ++j) {
            const long row = m0 + wr + mi * 16 + rbase + j;
            float v = acc[mi][ni][j];
            float o;
            if constexpr (MODE == 1) {
              if (col < 64)       o = tanhf(v);
              else if (col < 128) o = v;
              else if (col < 384) { float s = v + b1[col - 128]; o = 1.f / (1.f + expf(-s)); }
              else                o = v + b2[col - 384];
            } else {
              float s = v + b1[col];
              o = 0.5f * s * (1.f + erff(s * 0.70710678118654752f));
            }
            outp[row * N + col] = f2bf(o);
          }
          acc[mi][ni] = zero;
        }
      }
    }
  }
}

// ========== G2: C-mix GEMM (R2 shape): x += ys*g + dt*(1-g), x bf16 RMW ==========
// ys = hs[M,64] @ Cw[256,64]^T ; g,dt from zgd (stride 640, offsets 128/384)
__global__ __launch_bounds__(256)
void gemm_cmix(const ushort* __restrict__ A, const ushort* __restrict__ W,
               const ushort* __restrict__ zgd, ushort* __restrict__ x) {
  constexpr int K = 64;
  __shared__ __align__(16) ushort As[128 * 32];
  __shared__ __align__(16) ushort Ws[128 * 32];

  const int t = threadIdx.x, lane = t & 63, wid = t >> 6;
  const long m0 = (long)blockIdx.x * 128;
  const int n0 = blockIdx.y * 128;
  const int wr = (wid >> 1) * 64, wc = (wid & 1) * 64;
  const int c0 = wid * 2;
  const int r0 = c0 * 16 + (lane >> 2), r1 = r0 + 16;
  const int cb0 = (((lane & 3) ^ swzkey(r0)) << 4);
  const int cb1 = (((lane & 3) ^ swzkey(r1)) << 4);
  const char* Ab = (const char*)A;
  const char* Wb = (const char*)W;
  constexpr long K2 = (long)K * 2;

  const int krow = lane & 15, kslot = lane >> 4;
  int aoff[4], boff[4];
#pragma unroll
  for (int i = 0; i < 4; ++i) {
    int ar = wr + i * 16 + krow;
    aoff[i] = ar * 64 + ((kslot ^ swzkey(ar)) << 4);
    int br = wc + i * 16 + krow;
    boff[i] = br * 64 + ((kslot ^ swzkey(br)) << 4);
  }

  const f32x4_t zero = {0.f, 0.f, 0.f, 0.f};
  f32x4_t acc[4][4];
#pragma unroll
  for (int i = 0; i < 4; ++i)
#pragma unroll
    for (int j = 0; j < 4; ++j) acc[i][j] = zero;

  for (int k0 = 0; k0 < K; k0 += 32) {
    const long kb = (long)k0 * 2;
    gload_lds16(Ab + (m0 + r0) * K2 + kb + cb0, (char*)As + c0 * 1024);
    gload_lds16(Ab + (m0 + r1) * K2 + kb + cb1, (char*)As + c0 * 1024 + 1024);
    gload_lds16(Wb + (long)(n0 + r0) * K2 + kb + cb0, (char*)Ws + c0 * 1024);
    gload_lds16(Wb + (long)(n0 + r1) * K2 + kb + cb1, (char*)Ws + c0 * 1024 + 1024);
    __syncthreads();

    bf16x8_t af[4], bv[4];
#pragma unroll
    for (int i = 0; i < 4; ++i) af[i] = *(const bf16x8_t*)((const char*)As + aoff[i]);
#pragma unroll
    for (int i = 0; i < 4; ++i) bv[i] = *(const bf16x8_t*)((const char*)Ws + boff[i]);
#pragma unroll
    for (int mi = 0; mi < 4; ++mi)
#pragma unroll
      for (int ni = 0; ni < 4; ++ni)
        acc[mi][ni] = __builtin_amdgcn_mfma_f32_16x16x32_bf16(af[mi], bv[ni], acc[mi][ni], 0, 0, 0);
    __syncthreads();
  }

  const int rbase = (lane >> 4) * 4;
  const int cbase = lane & 15;
#pragma unroll
  for (int mi = 0; mi < 4; ++mi) {
#pragma unroll
    for (int ni = 0; ni < 4; ++ni) {
      const int col = n0 + wc + ni * 16 + cbase;
#pragma unroll
      for (int j = 0; j < 4; ++j) {
        const long row = m0 + wr + mi * 16 + rbase + j;
        float v = acc[mi][ni][j];
        float gv = bf2f(zgd[row * 640 + 128 + col]);
        float dv = bf2f(zgd[row * 640 + 384 + col]);
        float xo = bf2f(x[row * 256 + col]);
        x[row * 256 + col] = f2bf(xo + v * gv + dv * (1.f - gv));
      }
    }
  }
}

// ========== G3: N=256 full-row GEMM with fused residual + LayerNorm (x bf16) ==========
// MODE 0: xnew = v + b1[col]            MODE 3: xnew = x[row,col] + v + b1[col]
// Then per row: y = (xnew-mean)*rstd*lng + lnb; x written iff writex.
template <int K, int MODE>
__global__ __launch_bounds__(512)
void gemm_ln(const ushort* __restrict__ A, const ushort* __restrict__ W,
             const float* __restrict__ b1, ushort* __restrict__ x,
             const float* __restrict__ lng, const float* __restrict__ lnb,
             ushort* __restrict__ y, int writex) {
  constexpr int KS = K / 32;
  __shared__ __align__(16) char WsB[2 * 16384];
  __shared__ __align__(16) char AsB[2 * 8192];
  __shared__ float lsum4[128][4], lsq4[128][4];

  const int t = threadIdx.x, lane = t & 63, wid = t >> 6;
  const int wr = (wid >> 2) * 64, wc = (wid & 3) * 64;
  const int lr = lane >> 2, lc = lane & 3;
  const int ra = wid * 16 + lr;
  const int saA = (lc ^ swzkey(ra)) << 4;
  const int rw0 = wid * 32 + lr, rw1 = rw0 + 16;
  const int sw0 = (lc ^ swzkey(rw0)) << 4;
  const int sw1 = (lc ^ swzkey(rw1)) << 4;
  const char* Ab = (const char*)A;
  const char* Wb = (const char*)W;
  constexpr long K2 = (long)K * 2;
  const long m0 = (long)blockIdx.x * 128;

  gload_lds16(Wb + (long)rw0 * K2 + sw0, WsB + wid * 2048);
  gload_lds16(Wb + (long)rw1 * K2 + sw1, WsB + wid * 2048 + 1024);
  gload_lds16(Ab + (m0 + ra) * K2 + saA, AsB + wid * 1024);

  const int krow = lane & 15, kslot = lane >> 4;
  int aoff[4], boff[4];
#pragma unroll
  for (int i = 0; i < 4; ++i) {
    int ar = wr + i * 16 + krow;
    aoff[i] = ar * 64 + ((kslot ^ swzkey(ar)) << 4);
    int br = wc + i * 16 + krow;
    boff[i] = br * 64 + ((kslot ^ swzkey(br)) << 4);
  }

  const f32x4_t zero = {0.f, 0.f, 0.f, 0.f};
  f32x4_t acc[4][4];
#pragma unroll
  for (int i = 0; i < 4; ++i)
#pragma unroll
    for (int j = 0; j < 4; ++j) acc[i][j] = zero;

  for (int tau = 0; tau < KS; ++tau) {
    __syncthreads();
    if (tau + 1 < KS) {
      const long kb = (long)(tau + 1) * 64;
      gload_lds16(Ab + (m0 + ra) * K2 + kb + saA, AsB + ((tau + 1) & 1) * 8192 + wid * 1024);
      char* wd = WsB + ((tau + 1) & 1) * 16384 + wid * 2048;
      gload_lds16(Wb + (long)rw0 * K2 + kb + sw0, wd);
      gload_lds16(Wb + (long)rw1 * K2 + kb + sw1, wd + 1024);
    }
    const char* Ac = AsB + (tau & 1) * 8192;
    const char* Wc = WsB + (tau & 1) * 16384;
    bf16x8_t af[4], bv[4];
#pragma unroll
    for (int i = 0; i < 4; ++i) af[i] = *(const bf16x8_t*)(Ac + aoff[i]);
#pragma unroll
    for (int i = 0; i < 4; ++i) bv[i] = *(const bf16x8_t*)(Wc + boff[i]);
#pragma unroll
    for (int mi = 0; mi < 4; ++mi)
#pragma unroll
      for (int ni = 0; ni < 4; ++ni)
        acc[mi][ni] = __builtin_amdgcn_mfma_f32_16x16x32_bf16(af[mi], bv[ni], acc[mi][ni], 0, 0, 0);
  }

  const int rbase = (lane >> 4) * 4;
  const int cbase = lane & 15;
  // 1) residual
#pragma unroll
  for (int mi = 0; mi < 4; ++mi) {
#pragma unroll
    for (int ni = 0; ni < 4; ++ni) {
      const int col = wc + ni * 16 + cbase;
#pragma unroll
      for (int j = 0; j < 4; ++j) {
        const long row = m0 + wr + mi * 16 + rbase + j;
        float v = acc[mi][ni][j] + b1[col];
        if constexpr (MODE == 3) v += bf2f(x[row * 256 + col]);
        acc[mi][ni][j] = v;
      }
    }
  }
  // 2) per-row partial stats
#pragma unroll
  for (int mi = 0; mi < 4; ++mi) {
#pragma unroll
    for (int j = 0; j < 4; ++j) {
      float ps = 0.f, pq = 0.f;
#pragma unroll
      for (int ni = 0; ni < 4; ++ni) { float v = acc[mi][ni][j]; ps += v; pq += v * v; }
#pragma unroll
      for (int off = 1; off < 16; off <<= 1) {
        ps += __shfl_xor(ps, off, 64);
        pq += __shfl_xor(pq, off, 64);
      }
      if ((lane & 15) == 0) {
        int r = wr + mi * 16 + (lane >> 4) * 4 + j;
        lsum4[r][wid & 3] = ps;
        lsq4[r][wid & 3] = pq;
      }
    }
  }
  __syncthreads();
  // 3) normalize + store
#pragma unroll
  for (int mi = 0; mi < 4; ++mi) {
#pragma unroll
    for (int j = 0; j < 4; ++j) {
      const int r = wr + mi * 16 + rbase + j;
      const float s = lsum4[r][0] + lsum4[r][1] + lsum4[r][2] + lsum4[r][3];
      const float q = lsq4[r][0] + lsq4[r][1] + lsq4[r][2] + lsq4[r][3];
      const float mean = s * (1.f / 256.f);
      const float rstd = rsqrtf(q * (1.f / 256.f) - mean * mean + 1e-5f);
      const long row = m0 + r;
#pragma unroll
      for (int ni = 0; ni < 4; ++ni) {
        const int col = wc + ni * 16 + cbase;
        const float v = acc[mi][ni][j];
        if (writex) x[row * 256 + col] = f2bf(v);
        y[row * 256 + col] = f2bf((v - mean) * rstd * lng[col] + lnb[col]);
      }
    }
  }
}

// ---------------- LayerNorm: bf16 in -> bf16 out, one wave per 256-wide row ----------------
__global__ __launch_bounds__(256)
void ln_kernel(const ushort* __restrict__ x, const float* __restrict__ g,
               const float* __restrict__ b, ushort* __restrict__ y) {
  const int lane = threadIdx.x & 63;
  const long row = (long)blockIdx.x * 4 + (threadIdx.x >> 6);
  const ushort4 u = *(const ushort4*)(x + row * 256 + lane * 4);
  float v0 = bf2f(u.x), v1 = bf2f(u.y), v2 = bf2f(u.z), v3 = bf2f(u.w);
  float s = v0 + v1 + v2 + v3;
  float q = v0 * v0 + v1 * v1 + v2 * v2 + v3 * v3;
#pragma unroll
  for (int off = 32; off > 0; off >>= 1) {
    s += __shfl_xor(s, off, 64);
    q += __shfl_xor(q, off, 64);
  }
  const float mean = s * (1.f / 256.f);
  const float rstd = rsqrtf(q * (1.f / 256.f) - mean * mean + 1e-5f);
  const int c = lane * 4;
  const float4 gv = *(const float4*)(g + c);
  const float4 bv = *(const float4*)(b + c);
  ushort4 o;
  o.x = f2bf((v0 - mean) * rstd * gv.x + bv.x);
  o.y = f2bf((v1 - mean) * rstd * gv.y + bv.y);
  o.z = f2bf((v2 - mean) * rstd * gv.z + bv.z);
  o.w = f2bf((v3 - mean) * rstd * gv.w + bv.w);
  *(ushort4*)(y + row * 256 + c) = o;
}

// ---------------- scan ----------------
__global__ __launch_bounds__(256)
void scan_kernel(const ushort* __restrict__ z, ushort* __restrict__ hs) {
  const long tid = (long)blockIdx.x * 256 + threadIdx.x;
  const long b = tid >> 6;
  const int d = tid & 63;
  const ushort* zb = z + b * (16 * 640);
  ushort* hb = hs + b * (16 * 64);
  float h = 0.f;
#pragma unroll
  for (int s = 0; s < 16; ++s) {
    float a  = bf2f(zb[s * 640 + d]);
    float bt = bf2f(zb[s * 640 + 64 + d]);
    h = fmaf(a, h, bt);
    hb[s * 64 + d] = f2bf(h);
  }
}

// ---------------- head ----------------
__global__ __launch_bounds__(256)
void head_kernel(const ushort* __restrict__ yin, const float* __restrict__ attw,
                 const float* __restrict__ ow, const float* __restrict__ ob,
                 const float* __restrict__ cw, const float* __restrict__ cb,
                 float* __restrict__ out) {
  __shared__ float xf[16][256];
  __shared__ float lg[16], aw[16];
  __shared__ float vs[256], o1[128], lgc[40], lse[1];
  const int t = threadIdx.x, lane = t & 63, wid = t >> 6;
  const ushort* yb = yin + (long)blockIdx.x * 16 * 256;

  for (int r = wid; r < 16; r += 4) {
    ushort4 u = *(const ushort4*)(yb + r * 256 + lane * 4);
    int c = lane * 4;
    xf[r][c + 0] = bf2f(u.x);
    xf[r][c + 1] = bf2f(u.y);
    xf[r][c + 2] = bf2f(u.z);
    xf[r][c + 3] = bf2f(u.w);
  }
  __syncthreads();

  for (int r = wid; r < 16; r += 4) {
    const float* wv = attw + (r == 0 ? 0 : 256);
    int c = lane * 4;
    float s = xf[r][c] * wv[c] + xf[r][c + 1] * wv[c + 1] +
              xf[r][c + 2] * wv[c + 2] + xf[r][c + 3] * wv[c + 3];
#pragma unroll
    for (int off = 32; off > 0; off >>= 1) s += __shfl_xor(s, off, 64);
    if (lane == 0) lg[r] = s;
  }
  __syncthreads();

  if (t == 0) {
    float mx = -1e30f;
    for (int s2 = 1; s2 < 16; ++s2) mx = fmaxf(mx, lg[s2]);
    float den = 0.f;
    for (int s2 = 1; s2 < 16; ++s2) { float e = expf(lg[s2] - mx); aw[s2] = e; den += e; }
    float inv = 1.f / den;
    for (int s2 = 1; s2 < 16; ++s2) aw[s2] *= inv;
  }
  __syncthreads();

  float vh = xf[0][t];
  for (int s2 = 1; s2 < 16; ++s2) vh += aw[s2] * xf[s2][t];
  vs[t] = vh;
  __syncthreads();

  if (t < 128) {
    float s = ob[t];
    const float* w = ow + t * 256;
    for (int h2 = 0; h2 < 256; ++h2) s += w[h2] * vs[h2];
    o1[t] = fmaxf(s, 0.f);
  }
  __syncthreads();

  if (t < 40) {
    float s = cb[t];
    const float* w = cw + t * 128;
    for (int j = 0; j < 128; ++j) s += w[j] * o1[j];
    lgc[t] = s;
  }
  __syncthreads();

  if (t == 0) {
    float mx = -1e30f;
    for (int c2 = 0; c2 < 40; ++c2) mx = fmaxf(mx, lgc[c2]);
    float den = 0.f;
    for (int c2 = 0; c2 < 40; ++c2) den += expf(lgc[c2] - mx);
    lse[0] = mx + logf(den);
  }
  __syncthreads();
  if (t < 40) out[(long)blockIdx.x * 40 + t] = lgc[t] - lse[0];
}

// ---------------- host ----------------
extern "C" void kernel_launch(void* const* d_in, const int* in_sizes, int n_in,
                              void* d_out, int out_size, void* d_ws, size_t ws_size,
                              hipStream_t stream) {
  const float* data   = (const float*)d_in[0];
  const float* in_w   = (const float*)d_in[1];
  const float* in_b   = (const float*)d_in[2];
  const float* norm_g = (const float*)d_in[3];
  const float* norm_b = (const float*)d_in[4];
  const float* A_w    = (const float*)d_in[5];
  const float* B_w    = (const float*)d_in[6];
  const float* C_w    = (const float*)d_in[7];
  const float* D_w    = (const float*)d_in[8];
  const float* D_b    = (const float*)d_in[9];
  const float* gate_w = (const float*)d_in[10];
  const float* gate_b = (const float*)d_in[11];
  const float* ffn_w1 = (const float*)d_in[12];
  const float* ffn_b1 = (const float*)d_in[13];
  const float* ffn_w2 = (const float*)d_in[14];
  const float* ffn_b2 = (const float*)d_in[15];
  const float* fln_g  = (const float*)d_in[16];
  const float* fln_b  = (const float*)d_in[17];
  const float* out_w  = (const float*)d_in[18];
  const float* out_b  = (const float*)d_in[19];
  const float* cls_w  = (const float*)d_in[20];
  const float* cls_b  = (const float*)d_in[21];
  const float* attn_w = (const float*)d_in[22];
  const float* attn_b = (const float*)d_in[23];
  (void)in_sizes; (void)n_in; (void)out_size; (void)ws_size; (void)attn_b;

  char* ws = (char*)d_ws;
  ushort* x    = (ushort*)(ws + 0);           // 131072*256*2  =  67108864
  ushort* y    = (ushort*)(ws + 67108864);    // 131072*256*2  =  67108864
  ushort* z    = (ushort*)(ws + 134217728);   // 131072*640*2  = 167772160 (reused: datab, ffn1 t)
  ushort* hs   = (ushort*)(ws + 301989888);   // 131072*64*2   =  16777216
  ushort* wcat = (ushort*)(ws + 318767104);   // 6*640*256*2   =   1966080
  ushort* inwb = (ushort*)(ws + 320733184);   // 256*512*2     =    262144
  ushort* w1b  = (ushort*)(ws + 320995328);   // 6*512*256*2   =   1572864
  ushort* w2b  = (ushort*)(ws + 322568192);   // 6*256*512*2   =   1572864
  ushort* cwb  = (ushort*)(ws + 324141056);   // 6*256*64*2    =    196608
  ushort* datab = z;                          // consumed by input proj before z written

  cvt_kernel<<<512, 256, 0, stream>>>(in_w, inwb, 131072);
  cvt_kernel<<<3072, 256, 0, stream>>>(ffn_w1, w1b, 786432);
  cvt_kernel<<<3072, 256, 0, stream>>>(ffn_w2, w2b, 786432);
  cvt_kernel<<<384, 256, 0, stream>>>(C_w, cwb, 98304);
  build_wcat<<<3840, 256, 0, stream>>>(A_w, B_w, gate_w, D_w, wcat);
  cvt4_kernel<<<65536, 256, 0, stream>>>(data, datab, 16777216);

  // input proj + fused LN(layer0): x(bf16), y
  gemm_ln<512, 0><<<dim3(1024), 512, 0, stream>>>(
      datab, inwb, in_b, x, norm_g, norm_b, y, 1);

  for (int l = 0; l < 6; ++l) {
    gemm_wres<256, 1><<<dim3(256, 5), 256, 0, stream>>>(
        y, wcat + (size_t)l * 640 * 256, gate_b + l * 256, D_b + l * 256, z, 640, 4);
    scan_kernel<<<2048, 256, 0, stream>>>(z, hs);
    gemm_cmix<<<dim3(1024, 2), 256, 0, stream>>>(
        hs, cwb + (size_t)l * 256 * 64, z, x);
    ln_kernel<<<32768, 256, 0, stream>>>(x, norm_g + l * 256, norm_b + l * 256, y);
    gemm_wres<256, 2><<<dim3(256, 4), 256, 0, stream>>>(
        y, w1b + (size_t)l * 512 * 256, ffn_b1 + l * 512, nullptr, z, 512, 4);
    const float* lg2 = (l < 5) ? (norm_g + (l + 1) * 256) : fln_g;
    const float* lb2 = (l < 5) ? (norm_b + (l + 1) * 256) : fln_b;
    gemm_ln<512, 3><<<dim3(1024), 512, 0, stream>>>(
        z, w2b + (size_t)l * 256 * 512, ffn_b2 + l * 256, x, lg2, lb2, y, (l < 5) ? 1 : 0);
  }

  head_kernel<<<8192, 256, 0, stream>>>(y, attn_w, out_w, out_b, cls_w, cls_b, (float*)d_out);
}

// Round 5
// 3281.779 us; speedup vs baseline: 1.7525x; 1.0288x over previous
//
#include <hip/hip_runtime.h>

typedef __attribute__((ext_vector_type(8))) short bf16x8_t;
typedef __attribute__((ext_vector_type(4))) float f32x4_t;

__device__ __forceinline__ ushort f2bf(float x) {
  union { float f; unsigned u; } a; a.f = x;
  unsigned r = a.u + 0x7fffu + ((a.u >> 16) & 1u);
  return (ushort)(r >> 16);
}
__device__ __forceinline__ float bf2f(ushort s) {
  union { unsigned u; float f; } a; a.u = ((unsigned)s) << 16;
  return a.f;
}
__device__ __forceinline__ void gload_lds16(const void* g, void* l) {
  __builtin_amdgcn_global_load_lds(
      (const __attribute__((address_space(1))) unsigned int*)g,
      (__attribute__((address_space(3))) unsigned int*)l, 16, 0, 0);
}
__device__ __forceinline__ int swzkey(int r) { return ((r >> 2) ^ r) & 3; }

// ---------------- weight conversion ----------------
__global__ void cvt_kernel(const float* __restrict__ s, ushort* __restrict__ d, int n) {
  int i = blockIdx.x * 256 + threadIdx.x;
  if (i < n) d[i] = f2bf(s[i]);
}

__global__ void cvt4_kernel(const float* __restrict__ s, ushort* __restrict__ d, long n4) {
  long i = (long)blockIdx.x * 256 + threadIdx.x;
  if (i < n4) {
    float4 v = ((const float4*)s)[i];
    ushort4 o;
    o.x = f2bf(v.x); o.y = f2bf(v.y); o.z = f2bf(v.z); o.w = f2bf(v.w);
    ((ushort4*)d)[i] = o;
  }
}

// Wcat[l][r][c], r: 0-63 A_w, 64-127 B_w, 128-383 gate_w, 384-639 D_w
__global__ void build_wcat(const float* __restrict__ Aw, const float* __restrict__ Bw,
                           const float* __restrict__ gw, const float* __restrict__ Dw,
                           ushort* __restrict__ out) {
  int i = blockIdx.x * 256 + threadIdx.x;
  if (i >= 6 * 640 * 256) return;
  int l = i / (640 * 256), r = (i / 256) % 640, c = i % 256;
  float v;
  if (r < 64)        v = Aw[((l * 64 + r) * 256) + c];
  else if (r < 128)  v = Bw[((l * 64 + (r - 64)) * 256) + c];
  else if (r < 384)  v = gw[((l * 256 + (r - 128)) * 256) + c];
  else               v = Dw[((l * 256 + (r - 384)) * 256) + c];
  out[i] = f2bf(v);
}

// ========== G1: A-stationary GEMM (K=256). A tile 128xK resident in LDS; W streamed
// from L2 in 8KB k-slices, double-buffered. Block covers all NP n-panels.
// MODE 1: bf16 out, col<64 tanh | <128 id | <384 sigmoid(v+b1[col-128]) | else v+b2[col-384]
// MODE 2: bf16 out = gelu_exact(v + b1[col])
template <int NP, int MODE>
__global__ __launch_bounds__(256, 2)
void gemm_astat(const ushort* __restrict__ A, const ushort* __restrict__ W,
                const float* __restrict__ b1, const float* __restrict__ b2,
                ushort* __restrict__ outp) {
  constexpr int N = NP * 128;
  constexpr int KS = 8;                  // 256 / 32
  __shared__ __align__(16) char AsB[128 * 512];   // resident A: row r at r*512, 32 slots
  __shared__ __align__(16) char WsB[2 * 8192];    // W double buffer: 128 rows x 64B

  const int t = threadIdx.x, lane = t & 63, wid = t >> 6;
  const long m0 = (long)blockIdx.x * 128;
  const int wr = (wid >> 1) * 64, wc = (wid & 1) * 64;
  const char* Ab = (const char*)A;
  const char* Wb = (const char*)W;

  // ---- stage resident A: 16 rounds x 4KB; wave covers 2 rows (32 slots each) ----
  {
    const int arow = lane >> 5;          // +0/1 within wave
    const int aps  = lane & 31;          // physical 16B slot
#pragma unroll
    for (int j = 0; j < 16; ++j) {
      const int r = j * 8 + wid * 2 + arow;
      gload_lds16(Ab + (m0 + r) * 512 + (long)((aps ^ (r & 7)) << 4),
                  AsB + (j * 8 + wid * 2) * 512);
    }
  }

  // ---- W staging pattern (16-row x 64B chunks, 2 per wave) ----
  const int lr = lane >> 2, lc = lane & 3;
  const int ca = wid * 2;
  const int rw0 = ca * 16 + lr, rw1 = rw0 + 16;
  const int sw0 = (lc ^ swzkey(rw0)) << 4;
  const int sw1 = (lc ^ swzkey(rw1)) << 4;

  // ---- fragment read offsets ----
  const int krow = lane & 15, kslot = lane >> 4;
  int arbase[4], arkey[4], boff[4];
#pragma unroll
  for (int i = 0; i < 4; ++i) {
    const int ar = wr + i * 16 + krow;
    arbase[i] = ar * 512;
    arkey[i] = ar & 7;
    const int br = wc + i * 16 + krow;
    boff[i] = br * 64 + ((kslot ^ swzkey(br)) << 4);
  }

  const f32x4_t zero = {0.f, 0.f, 0.f, 0.f};
  f32x4_t acc[4][4];
#pragma unroll
  for (int i = 0; i < 4; ++i)
#pragma unroll
    for (int j = 0; j < 4; ++j) acc[i][j] = zero;

  constexpr int T = NP * KS;
  // stage W(0)
  gload_lds16(Wb + (long)rw0 * 512 + sw0, WsB + ca * 1024);
  gload_lds16(Wb + (long)rw1 * 512 + sw1, WsB + ca * 1024 + 1024);

  const int rbase = (lane >> 4) * 4;
  const int cbase = lane & 15;

  for (int tau = 0; tau < T; ++tau) {
    __syncthreads();
    if (tau + 1 < T) {
      const int np1 = (tau + 1) >> 3;
      const long kb1 = (long)((tau + 1) & 7) * 64;
      char* buf = WsB + ((tau + 1) & 1) * 8192;
      gload_lds16(Wb + (long)(np1 * 128 + rw0) * 512 + kb1 + sw0, buf + ca * 1024);
      gload_lds16(Wb + (long)(np1 * 128 + rw1) * 512 + kb1 + sw1, buf + ca * 1024 + 1024);
    }
    const int ks = tau & 7;
    const char* Wc = WsB + (tau & 1) * 8192;
    bf16x8_t af[4], bv[4];
#pragma unroll
    for (int i = 0; i < 4; ++i)
      af[i] = *(const bf16x8_t*)(AsB + arbase[i] + ((((ks << 2) | kslot) ^ arkey[i]) << 4));
#pragma unroll
    for (int i = 0; i < 4; ++i) bv[i] = *(const bf16x8_t*)(Wc + boff[i]);
#pragma unroll
    for (int mi = 0; mi < 4; ++mi)
#pragma unroll
      for (int ni = 0; ni < 4; ++ni)
        acc[mi][ni] = __builtin_amdgcn_mfma_f32_16x16x32_bf16(af[mi], bv[ni], acc[mi][ni], 0, 0, 0);

    if (ks == KS - 1) {
      const int np = tau >> 3;
#pragma unroll
      for (int mi = 0; mi < 4; ++mi) {
#pragma unroll
        for (int ni = 0; ni < 4; ++ni) {
          const int col = np * 128 + wc + ni * 16 + cbase;
#pragma unroll
          for (int j = 0; j < 4; ++j) {
            const long row = m0 + wr + mi * 16 + rbase + j;
            float v = acc[mi][ni][j];
            float o;
            if constexpr (MODE == 1) {
              if (col < 64)       o = tanhf(v);
              else if (col < 128) o = v;
              else if (col < 384) { float s = v + b1[col - 128]; o = 1.f / (1.f + expf(-s)); }
              else                o = v + b2[col - 384];
            } else {
              float s = v + b1[col];
              o = 0.5f * s * (1.f + erff(s * 0.70710678118654752f));
            }
            outp[row * N + col] = f2bf(o);
          }
          acc[mi][ni] = zero;
        }
      }
    }
  }
}

// ========== G2: C-mix GEMM: x += ys*g + dt*(1-g), x bf16 RMW ==========
__global__ __launch_bounds__(256)
void gemm_cmix(const ushort* __restrict__ A, const ushort* __restrict__ W,
               const ushort* __restrict__ zgd, ushort* __restrict__ x) {
  constexpr int K = 64;
  __shared__ __align__(16) ushort As[128 * 32];
  __shared__ __align__(16) ushort Ws[128 * 32];

  const int t = threadIdx.x, lane = t & 63, wid = t >> 6;
  const long m0 = (long)blockIdx.x * 128;
  const int n0 = blockIdx.y * 128;
  const int wr = (wid >> 1) * 64, wc = (wid & 1) * 64;
  const int c0 = wid * 2;
  const int r0 = c0 * 16 + (lane >> 2), r1 = r0 + 16;
  const int cb0 = (((lane & 3) ^ swzkey(r0)) << 4);
  const int cb1 = (((lane & 3) ^ swzkey(r1)) << 4);
  const char* Ab = (const char*)A;
  const char* Wb = (const char*)W;
  constexpr long K2 = (long)K * 2;

  const int krow = lane & 15, kslot = lane >> 4;
  int aoff[4], boff[4];
#pragma unroll
  for (int i = 0; i < 4; ++i) {
    int ar = wr + i * 16 + krow;
    aoff[i] = ar * 64 + ((kslot ^ swzkey(ar)) << 4);
    int br = wc + i * 16 + krow;
    boff[i] = br * 64 + ((kslot ^ swzkey(br)) << 4);
  }

  const f32x4_t zero = {0.f, 0.f, 0.f, 0.f};
  f32x4_t acc[4][4];
#pragma unroll
  for (int i = 0; i < 4; ++i)
#pragma unroll
    for (int j = 0; j < 4; ++j) acc[i][j] = zero;

  for (int k0 = 0; k0 < K; k0 += 32) {
    const long kb = (long)k0 * 2;
    gload_lds16(Ab + (m0 + r0) * K2 + kb + cb0, (char*)As + c0 * 1024);
    gload_lds16(Ab + (m0 + r1) * K2 + kb + cb1, (char*)As + c0 * 1024 + 1024);
    gload_lds16(Wb + (long)(n0 + r0) * K2 + kb + cb0, (char*)Ws + c0 * 1024);
    gload_lds16(Wb + (long)(n0 + r1) * K2 + kb + cb1, (char*)Ws + c0 * 1024 + 1024);
    __syncthreads();

    bf16x8_t af[4], bv[4];
#pragma unroll
    for (int i = 0; i < 4; ++i) af[i] = *(const bf16x8_t*)((const char*)As + aoff[i]);
#pragma unroll
    for (int i = 0; i < 4; ++i) bv[i] = *(const bf16x8_t*)((const char*)Ws + boff[i]);
#pragma unroll
    for (int mi = 0; mi < 4; ++mi)
#pragma unroll
      for (int ni = 0; ni < 4; ++ni)
        acc[mi][ni] = __builtin_amdgcn_mfma_f32_16x16x32_bf16(af[mi], bv[ni], acc[mi][ni], 0, 0, 0);
    __syncthreads();
  }

  const int rbase = (lane >> 4) * 4;
  const int cbase = lane & 15;
#pragma unroll
  for (int mi = 0; mi < 4; ++mi) {
#pragma unroll
    for (int ni = 0; ni < 4; ++ni) {
      const int col = n0 + wc + ni * 16 + cbase;
#pragma unroll
      for (int j = 0; j < 4; ++j) {
        const long row = m0 + wr + mi * 16 + rbase + j;
        float v = acc[mi][ni][j];
        float gv = bf2f(zgd[row * 640 + 128 + col]);
        float dv = bf2f(zgd[row * 640 + 384 + col]);
        float xo = bf2f(x[row * 256 + col]);
        x[row * 256 + col] = f2bf(xo + v * gv + dv * (1.f - gv));
      }
    }
  }
}

// ========== G3: N=256 full-row GEMM with fused residual + LayerNorm (x bf16) ==========
// MODE 0: xnew = v + b1[col]            MODE 3: xnew = x[row,col] + v + b1[col]
template <int K, int MODE>
__global__ __launch_bounds__(512)
void gemm_ln(const ushort* __restrict__ A, const ushort* __restrict__ W,
             const float* __restrict__ b1, ushort* __restrict__ x,
             const float* __restrict__ lng, const float* __restrict__ lnb,
             ushort* __restrict__ y, int writex) {
  constexpr int KS = K / 32;
  __shared__ __align__(16) char WsB[2 * 16384];
  __shared__ __align__(16) char AsB[2 * 8192];
  __shared__ float lsum4[128][4], lsq4[128][4];

  const int t = threadIdx.x, lane = t & 63, wid = t >> 6;
  const int wr = (wid >> 2) * 64, wc = (wid & 3) * 64;
  const int lr = lane >> 2, lc = lane & 3;
  const int ra = wid * 16 + lr;
  const int saA = (lc ^ swzkey(ra)) << 4;
  const int rw0 = wid * 32 + lr, rw1 = rw0 + 16;
  const int sw0 = (lc ^ swzkey(rw0)) << 4;
  const int sw1 = (lc ^ swzkey(rw1)) << 4;
  const char* Ab = (const char*)A;
  const char* Wb = (const char*)W;
  constexpr long K2 = (long)K * 2;
  const long m0 = (long)blockIdx.x * 128;

  gload_lds16(Wb + (long)rw0 * K2 + sw0, WsB + wid * 2048);
  gload_lds16(Wb + (long)rw1 * K2 + sw1, WsB + wid * 2048 + 1024);
  gload_lds16(Ab + (m0 + ra) * K2 + saA, AsB + wid * 1024);

  const int krow = lane & 15, kslot = lane >> 4;
  int aoff[4], boff[4];
#pragma unroll
  for (int i = 0; i < 4; ++i) {
    int ar = wr + i * 16 + krow;
    aoff[i] = ar * 64 + ((kslot ^ swzkey(ar)) << 4);
    int br = wc + i * 16 + krow;
    boff[i] = br * 64 + ((kslot ^ swzkey(br)) << 4);
  }

  const f32x4_t zero = {0.f, 0.f, 0.f, 0.f};
  f32x4_t acc[4][4];
#pragma unroll
  for (int i = 0; i < 4; ++i)
#pragma unroll
    for (int j = 0; j < 4; ++j) acc[i][j] = zero;

  for (int tau = 0; tau < KS; ++tau) {
    __syncthreads();
    if (tau + 1 < KS) {
      const long kb = (long)(tau + 1) * 64;
      gload_lds16(Ab + (m0 + ra) * K2 + kb + saA, AsB + ((tau + 1) & 1) * 8192 + wid * 1024);
      char* wd = WsB + ((tau + 1) & 1) * 16384 + wid * 2048;
      gload_lds16(Wb + (long)rw0 * K2 + kb + sw0, wd);
      gload_lds16(Wb + (long)rw1 * K2 + kb + sw1, wd + 1024);
    }
    const char* Ac = AsB + (tau & 1) * 8192;
    const char* Wc = WsB + (tau & 1) * 16384;
    bf16x8_t af[4], bv[4];
#pragma unroll
    for (int i = 0; i < 4; ++i) af[i] = *(const bf16x8_t*)(Ac + aoff[i]);
#pragma unroll
    for (int i = 0; i < 4; ++i) bv[i] = *(const bf16x8_t*)(Wc + boff[i]);
#pragma unroll
    for (int mi = 0; mi < 4; ++mi)
#pragma unroll
      for (int ni = 0; ni < 4; ++ni)
        acc[mi][ni] = __builtin_amdgcn_mfma_f32_16x16x32_bf16(af[mi], bv[ni], acc[mi][ni], 0, 0, 0);
  }

  const int rbase = (lane >> 4) * 4;
  const int cbase = lane & 15;
#pragma unroll
  for (int mi = 0; mi < 4; ++mi) {
#pragma unroll
    for (int ni = 0; ni < 4; ++ni) {
      const int col = wc + ni * 16 + cbase;
#pragma unroll
      for (int j = 0; j < 4; ++j) {
        const long row = m0 + wr + mi * 16 + rbase + j;
        float v = acc[mi][ni][j] + b1[col];
        if constexpr (MODE == 3) v += bf2f(x[row * 256 + col]);
        acc[mi][ni][j] = v;
      }
    }
  }
#pragma unroll
  for (int mi = 0; mi < 4; ++mi) {
#pragma unroll
    for (int j = 0; j < 4; ++j) {
      float ps = 0.f, pq = 0.f;
#pragma unroll
      for (int ni = 0; ni < 4; ++ni) { float v = acc[mi][ni][j]; ps += v; pq += v * v; }
#pragma unroll
      for (int off = 1; off < 16; off <<= 1) {
        ps += __shfl_xor(ps, off, 64);
        pq += __shfl_xor(pq, off, 64);
      }
      if ((lane & 15) == 0) {
        int r = wr + mi * 16 + (lane >> 4) * 4 + j;
        lsum4[r][wid & 3] = ps;
        lsq4[r][wid & 3] = pq;
      }
    }
  }
  __syncthreads();
#pragma unroll
  for (int mi = 0; mi < 4; ++mi) {
#pragma unroll
    for (int j = 0; j < 4; ++j) {
      const int r = wr + mi * 16 + rbase + j;
      const float s = lsum4[r][0] + lsum4[r][1] + lsum4[r][2] + lsum4[r][3];
      const float q = lsq4[r][0] + lsq4[r][1] + lsq4[r][2] + lsq4[r][3];
      const float mean = s * (1.f / 256.f);
      const float rstd = rsqrtf(q * (1.f / 256.f) - mean * mean + 1e-5f);
      const long row = m0 + r;
#pragma unroll
      for (int ni = 0; ni < 4; ++ni) {
        const int col = wc + ni * 16 + cbase;
        const float v = acc[mi][ni][j];
        if (writex) x[row * 256 + col] = f2bf(v);
        y[row * 256 + col] = f2bf((v - mean) * rstd * lng[col] + lnb[col]);
      }
    }
  }
}

// ---------------- LayerNorm: bf16 in -> bf16 out ----------------
__global__ __launch_bounds__(256)
void ln_kernel(const ushort* __restrict__ x, const float* __restrict__ g,
               const float* __restrict__ b, ushort* __restrict__ y) {
  const int lane = threadIdx.x & 63;
  const long row = (long)blockIdx.x * 4 + (threadIdx.x >> 6);
  const ushort4 u = *(const ushort4*)(x + row * 256 + lane * 4);
  float v0 = bf2f(u.x), v1 = bf2f(u.y), v2 = bf2f(u.z), v3 = bf2f(u.w);
  float s = v0 + v1 + v2 + v3;
  float q = v0 * v0 + v1 * v1 + v2 * v2 + v3 * v3;
#pragma unroll
  for (int off = 32; off > 0; off >>= 1) {
    s += __shfl_xor(s, off, 64);
    q += __shfl_xor(q, off, 64);
  }
  const float mean = s * (1.f / 256.f);
  const float rstd = rsqrtf(q * (1.f / 256.f) - mean * mean + 1e-5f);
  const int c = lane * 4;
  const float4 gv = *(const float4*)(g + c);
  const float4 bv = *(const float4*)(b + c);
  ushort4 o;
  o.x = f2bf((v0 - mean) * rstd * gv.x + bv.x);
  o.y = f2bf((v1 - mean) * rstd * gv.y + bv.y);
  o.z = f2bf((v2 - mean) * rstd * gv.z + bv.z);
  o.w = f2bf((v3 - mean) * rstd * gv.w + bv.w);
  *(ushort4*)(y + row * 256 + c) = o;
}

// ---------------- scan ----------------
__global__ __launch_bounds__(256)
void scan_kernel(const ushort* __restrict__ z, ushort* __restrict__ hs) {
  const long tid = (long)blockIdx.x * 256 + threadIdx.x;
  const long b = tid >> 6;
  const int d = tid & 63;
  const ushort* zb = z + b * (16 * 640);
  ushort* hb = hs + b * (16 * 64);
  float h = 0.f;
#pragma unroll
  for (int s = 0; s < 16; ++s) {
    float a  = bf2f(zb[s * 640 + d]);
    float bt = bf2f(zb[s * 640 + 64 + d]);
    h = fmaf(a, h, bt);
    hb[s * 64 + d] = f2bf(h);
  }
}

// ---------------- head ----------------
__global__ __launch_bounds__(256)
void head_kernel(const ushort* __restrict__ yin, const float* __restrict__ attw,
                 const float* __restrict__ ow, const float* __restrict__ ob,
                 const float* __restrict__ cw, const float* __restrict__ cb,
                 float* __restrict__ out) {
  __shared__ float xf[16][256];
  __shared__ float lg[16], aw[16];
  __shared__ float vs[256], o1[128], lgc[40], lse[1];
  const int t = threadIdx.x, lane = t & 63, wid = t >> 6;
  const ushort* yb = yin + (long)blockIdx.x * 16 * 256;

  for (int r = wid; r < 16; r += 4) {
    ushort4 u = *(const ushort4*)(yb + r * 256 + lane * 4);
    int c = lane * 4;
    xf[r][c + 0] = bf2f(u.x);
    xf[r][c + 1] = bf2f(u.y);
    xf[r][c + 2] = bf2f(u.z);
    xf[r][c + 3] = bf2f(u.w);
  }
  __syncthreads();

  for (int r = wid; r < 16; r += 4) {
    const float* wv = attw + (r == 0 ? 0 : 256);
    int c = lane * 4;
    float s = xf[r][c] * wv[c] + xf[r][c + 1] * wv[c + 1] +
              xf[r][c + 2] * wv[c + 2] + xf[r][c + 3] * wv[c + 3];
#pragma unroll
    for (int off = 32; off > 0; off >>= 1) s += __shfl_xor(s, off, 64);
    if (lane == 0) lg[r] = s;
  }
  __syncthreads();

  if (t == 0) {
    float mx = -1e30f;
    for (int s2 = 1; s2 < 16; ++s2) mx = fmaxf(mx, lg[s2]);
    float den = 0.f;
    for (int s2 = 1; s2 < 16; ++s2) { float e = expf(lg[s2] - mx); aw[s2] = e; den += e; }
    float inv = 1.f / den;
    for (int s2 = 1; s2 < 16; ++s2) aw[s2] *= inv;
  }
  __syncthreads();

  float vh = xf[0][t];
  for (int s2 = 1; s2 < 16; ++s2) vh += aw[s2] * xf[s2][t];
  vs[t] = vh;
  __syncthreads();

  if (t < 128) {
    float s = ob[t];
    const float* w = ow + t * 256;
    for (int h2 = 0; h2 < 256; ++h2) s += w[h2] * vs[h2];
    o1[t] = fmaxf(s, 0.f);
  }
  __syncthreads();

  if (t < 40) {
    float s = cb[t];
    const float* w = cw + t * 128;
    for (int j = 0; j < 128; ++j) s += w[j] * o1[j];
    lgc[t] = s;
  }
  __syncthreads();

  if (t == 0) {
    float mx = -1e30f;
    for (int c2 = 0; c2 < 40; ++c2) mx = fmaxf(mx, lgc[c2]);
    float den = 0.f;
    for (int c2 = 0; c2 < 40; ++c2) den += expf(lgc[c2] - mx);
    lse[0] = mx + logf(den);
  }
  __syncthreads();
  if (t < 40) out[(long)blockIdx.x * 40 + t] = lgc[t] - lse[0];
}

// ---------------- host ----------------
extern "C" void kernel_launch(void* const* d_in, const int* in_sizes, int n_in,
                              void* d_out, int out_size, void* d_ws, size_t ws_size,
                              hipStream_t stream) {
  const float* data   = (const float*)d_in[0];
  const float* in_w   = (const float*)d_in[1];
  const float* in_b   = (const float*)d_in[2];
  const float* norm_g = (const float*)d_in[3];
  const float* norm_b = (const float*)d_in[4];
  const float* A_w    = (const float*)d_in[5];
  const float* B_w    = (const float*)d_in[6];
  const float* C_w    = (const float*)d_in[7];
  const float* D_w    = (const float*)d_in[8];
  const float* D_b    = (const float*)d_in[9];
  const float* gate_w = (const float*)d_in[10];
  const float* gate_b = (const float*)d_in[11];
  const float* ffn_w1 = (const float*)d_in[12];
  const float* ffn_b1 = (const float*)d_in[13];
  const float* ffn_w2 = (const float*)d_in[14];
  const float* ffn_b2 = (const float*)d_in[15];
  const float* fln_g  = (const float*)d_in[16];
  const float* fln_b  = (const float*)d_in[17];
  const float* out_w  = (const float*)d_in[18];
  const float* out_b  = (const float*)d_in[19];
  const float* cls_w  = (const float*)d_in[20];
  const float* cls_b  = (const float*)d_in[21];
  const float* attn_w = (const float*)d_in[22];
  const float* attn_b = (const float*)d_in[23];
  (void)in_sizes; (void)n_in; (void)out_size; (void)ws_size; (void)attn_b;

  char* ws = (char*)d_ws;
  ushort* x    = (ushort*)(ws + 0);           // 131072*256*2  =  67108864
  ushort* y    = (ushort*)(ws + 67108864);    // 131072*256*2  =  67108864
  ushort* z    = (ushort*)(ws + 134217728);   // 131072*640*2  = 167772160 (reused: datab, ffn1 t)
  ushort* hs   = (ushort*)(ws + 301989888);   // 131072*64*2   =  16777216
  ushort* wcat = (ushort*)(ws + 318767104);   // 6*640*256*2   =   1966080
  ushort* inwb = (ushort*)(ws + 320733184);   // 256*512*2     =    262144
  ushort* w1b  = (ushort*)(ws + 320995328);   // 6*512*256*2   =   1572864
  ushort* w2b  = (ushort*)(ws + 322568192);   // 6*256*512*2   =   1572864
  ushort* cwb  = (ushort*)(ws + 324141056);   // 6*256*64*2    =    196608
  ushort* datab = z;                          // consumed by input proj before z written

  cvt_kernel<<<512, 256, 0, stream>>>(in_w, inwb, 131072);
  cvt_kernel<<<3072, 256, 0, stream>>>(ffn_w1, w1b, 786432);
  cvt_kernel<<<3072, 256, 0, stream>>>(ffn_w2, w2b, 786432);
  cvt_kernel<<<384, 256, 0, stream>>>(C_w, cwb, 98304);
  build_wcat<<<3840, 256, 0, stream>>>(A_w, B_w, gate_w, D_w, wcat);
  cvt4_kernel<<<65536, 256, 0, stream>>>(data, datab, 16777216);

  // input proj + fused LN(layer0): x(bf16), y
  gemm_ln<512, 0><<<dim3(1024), 512, 0, stream>>>(
      datab, inwb, in_b, x, norm_g, norm_b, y, 1);

  for (int l = 0; l < 6; ++l) {
    gemm_astat<5, 1><<<dim3(1024), 256, 0, stream>>>(
        y, wcat + (size_t)l * 640 * 256, gate_b + l * 256, D_b + l * 256, z);
    scan_kernel<<<2048, 256, 0, stream>>>(z, hs);
    gemm_cmix<<<dim3(1024, 2), 256, 0, stream>>>(
        hs, cwb + (size_t)l * 256 * 64, z, x);
    ln_kernel<<<32768, 256, 0, stream>>>(x, norm_g + l * 256, norm_b + l * 256, y);
    gemm_astat<4, 2><<<dim3(1024), 256, 0, stream>>>(
        y, w1b + (size_t)l * 512 * 256, ffn_b1 + l * 512, nullptr, z);
    const float* lg2 = (l < 5) ? (norm_g + (l + 1) * 256) : fln_g;
    const float* lb2 = (l < 5) ? (norm_b + (l + 1) * 256) : fln_b;
    gemm_ln<512, 3><<<dim3(1024), 512, 0, stream>>>(
        z, w2b + (size_t)l * 256 * 512, ffn_b2 + l * 256, x, lg2, lb2, y, (l < 5) ? 1 : 0);
  }

  head_kernel<<<8192, 256, 0, stream>>>(y, attn_w, out_w, out_b, cls_w, cls_b, (float*)d_out);
}